// Round 6
// baseline (1006.927 us; speedup 1.0000x reference)
//
#include <hip/hip_runtime.h>

#define NNODE 262144
#define NEDGE 1048576
#define NTILES 8192
#define NEG 0.01f

typedef __bf16 bf16x8 __attribute__((ext_vector_type(8)));
typedef float f32x4 __attribute__((ext_vector_type(4)));
typedef unsigned short u16;
typedef u16 u16x8 __attribute__((ext_vector_type(8)));
typedef unsigned int u32;

// native RNE f32->bf16 (compiler lowers to v_cvt_pk_bf16_f32 pairs on gfx950)
__device__ __forceinline__ u16 cvt_bf(float f) { return __builtin_bit_cast(u16, (__bf16)f); }
// order-preserving float->uint encoding for atomicMax; key 0 == "empty"
__device__ __forceinline__ u32 encf(float f) {
    u32 u = __float_as_uint(f);
    return (u & 0x80000000u) ? ~u : (u | 0x80000000u);
}
__device__ __forceinline__ float decf(u32 k) {
    return (k & 0x80000000u) ? __uint_as_float(k ^ 0x80000000u) : __uint_as_float(~k);
}
__device__ __forceinline__ float lrelu(float x) { return x >= 0.f ? x : NEG * x; }

// LDS-only barrier (verified safe R5): global loads/atomics stay in flight across it.
__device__ __forceinline__ void lgkm_bar() {
    asm volatile("s_waitcnt lgkmcnt(0)" ::: "memory");
    __builtin_amdgcn_s_barrier();
}

// bf16 MFMA fragment (A- or B-role; lane->(row/col=lane&15, k=(lane>>4)*8+j))
// from a global f32 matrix [K][Ncols], ld = Ncols. p = W + k0*ld + col.
template <int LD>
__device__ __forceinline__ bf16x8 load_bfrag(const float* __restrict__ p) {
    u16x8 t;
#pragma unroll
    for (int j = 0; j < 8; ++j) t[j] = cvt_bf(p[j * LD]);
    return __builtin_bit_cast(bf16x8, t);
}

// ---------------- K1: init out / gmax / denom (+ optional bf16 fea table) ----------------
template <bool TAB>
__global__ void k_init(const float* __restrict__ fea, float* __restrict__ out,
                       u32* __restrict__ gmaxk, float* __restrict__ denom,
                       u16* __restrict__ fea16) {
    int i = blockIdx.x * 256 + threadIdx.x;         // exactly N*16 float4 units
    float4 v = ((const float4*)fea)[i];
    ((float4*)out)[i] = v;                          // out starts at elem_in_fea
    if (TAB) {
        ushort4 s;
        s.x = cvt_bf(v.x); s.y = cvt_bf(v.y); s.z = cvt_bf(v.z); s.w = cvt_bf(v.w);
        ((ushort4*)fea16)[i] = s;
    }
    if (i < 3 * NNODE) { gmaxk[i] = 0u; denom[i] = 0.f; }
}

// ---------------- K2: gate logits, swapped GEMM + 2-tile prefetch pipeline ----------------
// 384 thr = 6 waves. Wave w: head w>>1, hidden block ntb=(w&1)*4 (64 hid cols), A=W1^T frags.
// C[row=hid q*4+r, col=edge c] -> per-lane dot with w2 -> 2-round q-shfl reduce.
template <bool TAB>
__global__ __launch_bounds__(384, 3) void k_gate(
    const float* __restrict__ fea, const u16* __restrict__ fea16,
    const int* __restrict__ selfi, const int* __restrict__ nbri,
    const float* __restrict__ gw1, const float* __restrict__ gb1,
    const float* __restrict__ gw2, const float* __restrict__ gb2,
    float* __restrict__ g_out, u32* __restrict__ gmaxk) {
    __shared__ u16 Al[128 * 136];
    __shared__ float gpart[6][128];
    const int tid = threadIdx.x;
    const int w = tid >> 6, l = tid & 63, q = l >> 4, c = l & 15;
    const int hw = w >> 1;
    const int ntb = (w & 1) * 4;

    bf16x8 wf[4][4];   // A-role W1^T frags: row = hid (ntb+t)*16+c, k = kk*32+q*8+j
    {
        const float* W = gw1 + hw * 16384;
#pragma unroll
        for (int t = 0; t < 4; ++t)
#pragma unroll
            for (int kk = 0; kk < 4; ++kk)
                wf[t][kk] = load_bfrag<128>(W + (kk * 32 + q * 8) * 128 + (ntb + t) * 16 + c);
    }
    float4 b1q[4], w2q[4];  // per-lane hid rows (ntb+t)*16 + q*4 .. +3
#pragma unroll
    for (int t = 0; t < 4; ++t) {
        b1q[t] = *(const float4*)(gb1 + hw * 128 + (ntb + t) * 16 + q * 4);
        w2q[t] = *(const float4*)(gw2 + hw * 128 + (ntb + t) * 16 + q * 4);
    }

    // staging geometry: 384 % 16 == 0 -> part is slot-invariant
    const int part = tid & 15;
    const int c8 = (part & 7) << 3;
    const int colw = ((part >> 3) << 6) + c8;
    const bool isSelf = part < 8;
    const int el0 = tid >> 4;               // el_[it] = el0 + it*24
    const bool v5 = tid < 128;              // slot 5 validity
    const int STRIDE = gridDim.x;

    int iv[6];
    u16x8 gT[6]; float4 gA[6], gB[6];

    auto loadIdx = [&](int tt) {
#pragma unroll
        for (int it = 0; it < 6; ++it) {
            if (it < 5 || v5) {
                int edge = tt * 128 + el0 + it * 24;
                iv[it] = isSelf ? selfi[edge] : nbri[edge];
            }
        }
    };
    auto issueGather = [&]() {
#pragma unroll
        for (int it = 0; it < 6; ++it) {
            if (it < 5 || v5) {
                if (TAB) gT[it] = *(const u16x8*)(fea16 + (size_t)iv[it] * 64 + c8);
                else {
                    gA[it] = *(const float4*)(fea + (size_t)iv[it] * 64 + c8);
                    gB[it] = *(const float4*)(fea + (size_t)iv[it] * 64 + c8 + 4);
                }
            }
        }
    };
    auto commitStage = [&]() {
#pragma unroll
        for (int it = 0; it < 6; ++it) {
            if (it < 5 || v5) {
                u16x8 sv;
                if (TAB) sv = gT[it];
                else {
#pragma unroll
                    for (int j = 0; j < 4; ++j) { sv[j] = cvt_bf(gA[it][j]); sv[4 + j] = cvt_bf(gB[it][j]); }
                }
                *(u16x8*)(Al + (el0 + it * 24) * 136 + colw) = sv;
            }
        }
    };

    // prologue
    int t = blockIdx.x;
    int sGc = 0, sGn = 0;
    loadIdx(t);
    if (v5) sGc = selfi[t * 128 + tid];
    issueGather();                                  // waits on iv once
    { int t1 = t + STRIDE; if (t1 >= NTILES) t1 = t;
      loadIdx(t1);
      if (v5) sGn = selfi[t1 * 128 + tid]; }

    for (; t < NTILES; t += STRIDE) {
        commitStage();
        lgkm_bar();   // bar1: Al ready

        // issue next-tile loads (hide under compute)
        int t1 = t + STRIDE; if (t1 >= NTILES) t1 = t;
        int t2 = t1 + STRIDE; if (t2 >= NTILES) t2 = t1;
        issueGather();          // gathers(t1), iv holds indices(t1)
        loadIdx(t2);            // indices(t2)
        int sUse = sGc; sGc = sGn;
        if (v5) sGn = selfi[t2 * 128 + tid];

#pragma unroll
        for (int eb = 0; eb < 8; ++eb) {
            const u16* arow = Al + (eb * 16 + c) * 136 + q * 8;
            bf16x8 e0 = *(const bf16x8*)(arow);
            bf16x8 e1 = *(const bf16x8*)(arow + 32);
            bf16x8 e2 = *(const bf16x8*)(arow + 64);
            bf16x8 e3 = *(const bf16x8*)(arow + 96);
            float gp = 0.f;
#pragma unroll
            for (int tt = 0; tt < 4; ++tt) {
                f32x4 acc = {0.f, 0.f, 0.f, 0.f};
                acc = __builtin_amdgcn_mfma_f32_16x16x32_bf16(wf[tt][0], e0, acc, 0, 0, 0);
                acc = __builtin_amdgcn_mfma_f32_16x16x32_bf16(wf[tt][1], e1, acc, 0, 0, 0);
                acc = __builtin_amdgcn_mfma_f32_16x16x32_bf16(wf[tt][2], e2, acc, 0, 0, 0);
                acc = __builtin_amdgcn_mfma_f32_16x16x32_bf16(wf[tt][3], e3, acc, 0, 0, 0);
                gp += lrelu(acc[0] + b1q[tt].x) * w2q[tt].x;
                gp += lrelu(acc[1] + b1q[tt].y) * w2q[tt].y;
                gp += lrelu(acc[2] + b1q[tt].z) * w2q[tt].z;
                gp += lrelu(acc[3] + b1q[tt].w) * w2q[tt].w;
            }
            gp += __shfl_xor(gp, 16, 64);
            gp += __shfl_xor(gp, 32, 64);
            if (q == 0) gpart[w][eb * 16 + c] = gp;
        }
        lgkm_bar();   // bar2: gpart ready; Al-read(t) done before stage-write(t+1)

        if (tid < 128) {
            int e = t * 128 + tid;
#pragma unroll
            for (int hh = 0; hh < 3; ++hh) {
                float g = gpart[2 * hh][tid] + gpart[2 * hh + 1][tid] + gb2[hh];
                g_out[hh * NEDGE + e] = g;
                atomicMax(gmaxk + hh * NNODE + sUse, encf(g));   // stays in flight
            }
        }
    }
}

// ---------------- K3: e = w*exp(g-gmax) (in place), denom += e ----------------
__global__ void k_denom(const float* __restrict__ ew,
                        const int* __restrict__ selfi, const int* __restrict__ nbri,
                        float* __restrict__ e_buf, const u32* __restrict__ gmaxk,
                        float* __restrict__ denom) {
    int t = blockIdx.x * 256 + threadIdx.x;   // M/4 threads
    int e0 = t * 4;
    int4 s4 = *(const int4*)(selfi + e0);
    int4 n4 = *(const int4*)(nbri + e0);
    float w0 = ew[n4.x], w1 = ew[n4.y], w2 = ew[n4.z], w3 = ew[n4.w];
#pragma unroll
    for (int h = 0; h < 3; ++h) {
        float4 g4 = *(const float4*)(e_buf + h * NEDGE + e0);
        const u32* gm = gmaxk + h * NNODE;
        float v0 = w0 * __expf(g4.x - decf(gm[s4.x]));
        float v1 = w1 * __expf(g4.y - decf(gm[s4.y]));
        float v2 = w2 * __expf(g4.z - decf(gm[s4.z]));
        float v3 = w3 * __expf(g4.w - decf(gm[s4.w]));
        float4 o = {v0, v1, v2, v3};
        *(float4*)(e_buf + h * NEDGE + e0) = o;
        float* dn = denom + h * NNODE;
        if (s4.x == s4.y) v1 += v0; else atomicAdd(dn + s4.x, v0);
        if (s4.y == s4.z) v2 += v1; else atomicAdd(dn + s4.y, v1);
        if (s4.z == s4.w) v3 += v2; else atomicAdd(dn + s4.z, v2);
        atomicAdd(dn + s4.w, v3);
    }
}

// ---------------- K4: messages + attn scatter, 1-tile register prefetch ----------------
template <bool TAB>
__global__ __launch_bounds__(512, 4) void k_msg(
    const float* __restrict__ fea, const u16* __restrict__ fea16,
    const int* __restrict__ selfi, const int* __restrict__ nbri,
    const float* __restrict__ mw1, const float* __restrict__ mb1,
    const float* __restrict__ mw2, const float* __restrict__ mb2,
    const float* __restrict__ e_buf, const float* __restrict__ denom,
    float* __restrict__ out) {
    __shared__ u16 Al[128 * 136];
    __shared__ u16 Hl[128 * 136];
    __shared__ float attn_l[2][128];
    __shared__ int self_l[2][128];
    const int h = blockIdx.y;
    const int tid = threadIdx.x;
    const int w = tid >> 6, l = tid & 63, q = l >> 4, c = l & 15;
    const int eg1 = w & 1, tg = w >> 1;        // GEMM1: 4 ebs, 2 hidden blocks
    const int eg2 = w >> 1, ng = w & 1;        // GEMM2: 2 ebs, 2 n2 blocks

    bf16x8 w1f[2][4];     // A-role W1^T frags: row = hid (tg*2+t')*16+c
    {
        const float* W1 = mw1 + h * 16384;
#pragma unroll
        for (int t = 0; t < 2; ++t)
#pragma unroll
            for (int kk = 0; kk < 4; ++kk)
                w1f[t][kk] = load_bfrag<128>(W1 + (kk * 32 + q * 8) * 128 + (tg * 2 + t) * 16 + c);
    }
    bf16x8 w2f[2][4];     // B-role frags: col = (ng*2+n2')*16+c
    {
        const float* W2 = mw2 + h * 8192;
#pragma unroll
        for (int n2 = 0; n2 < 2; ++n2)
#pragma unroll
            for (int kk = 0; kk < 4; ++kk)
                w2f[n2][kk] = load_bfrag<64>(W2 + (kk * 32 + q * 8) * 64 + (ng * 2 + n2) * 16 + c);
    }
    float4 b1q[2];
#pragma unroll
    for (int t = 0; t < 2; ++t)
        b1q[t] = *(const float4*)(mb1 + h * 128 + (tg * 2 + t) * 16 + q * 4);
    float b2v[2];
#pragma unroll
    for (int n2 = 0; n2 < 2; ++n2) b2v[n2] = mb2[h * 64 + (ng * 2 + n2) * 16 + c];

    // staging geometry: 512 % 16 == 0 -> part slot-invariant
    const int part = tid & 15;
    const int c8 = (part & 7) << 3;
    const int colw = ((part >> 3) << 6) + c8;
    const bool isSelf = part < 8;
    const int el0 = tid >> 4;                 // el_[it] = el0 + it*32
    const bool isAttn = tid < 128;
    const int STRIDE = gridDim.x;

    int iv[4];
    u16x8 gT[4]; float4 gA[4], gB[4];

    auto loadIdx = [&](int tt) {
#pragma unroll
        for (int it = 0; it < 4; ++it) {
            int edge = tt * 128 + el0 + it * 32;
            iv[it] = isSelf ? selfi[edge] : nbri[edge];
        }
    };
    auto issueGather = [&]() {
#pragma unroll
        for (int it = 0; it < 4; ++it) {
            if (TAB) gT[it] = *(const u16x8*)(fea16 + (size_t)iv[it] * 64 + c8);
            else {
                gA[it] = *(const float4*)(fea + (size_t)iv[it] * 64 + c8);
                gB[it] = *(const float4*)(fea + (size_t)iv[it] * 64 + c8 + 4);
            }
        }
    };
    auto commitStage = [&]() {
#pragma unroll
        for (int it = 0; it < 4; ++it) {
            u16x8 sv;
            if (TAB) sv = gT[it];
            else {
#pragma unroll
                for (int j = 0; j < 4; ++j) { sv[j] = cvt_bf(gA[it][j]); sv[4 + j] = cvt_bf(gB[it][j]); }
            }
            *(u16x8*)(Al + (el0 + it * 32) * 136 + colw) = sv;
        }
    };

    // prologue: fill pipeline for first tile
    int t = blockIdx.x;
    float ebv = 0.f, dnv = 1.f;
    int sAc = 0, sAn = 0;
    loadIdx(t);
    if (isAttn) sAc = selfi[t * 128 + tid];
    issueGather();                                  // one-time dependent wait
    if (isAttn) { ebv = e_buf[h * NEDGE + t * 128 + tid]; dnv = denom[h * NNODE + sAc]; }
    { int t1 = t + STRIDE; if (t1 >= NTILES) t1 = t;
      loadIdx(t1);
      if (isAttn) sAn = selfi[t1 * 128 + tid]; }

    int pb = 0;
    for (; t < NTILES; t += STRIDE, pb ^= 1) {
        // step 1: commit prefetched tile t
        commitStage();
        if (isAttn) {
            self_l[pb][tid] = sAc;
            attn_l[pb][tid] = ebv / (dnv + 1e-10f) * (1.f / 3.f);
        }
        lgkm_bar();   // bar1: Al+attn ready; all waves past GEMM2(t-1) Hl-reads

        // step 2: issue tile t+1 loads (resolve under GEMM compute)
        int t1 = t + STRIDE; if (t1 >= NTILES) t1 = t;
        int t2 = t1 + STRIDE; if (t2 >= NTILES) t2 = t1;
        issueGather();                        // gathers(t1); iv = indices(t1) ready
        if (isAttn) { ebv = e_buf[h * NEDGE + t1 * 128 + tid]; dnv = denom[h * NNODE + sAn]; }
        loadIdx(t2);                          // indices(t2)
        if (isAttn) { sAc = sAn; sAn = selfi[t2 * 128 + tid]; }

        // ---- GEMM1 swapped: C[row=hid, col=edge]; packed b64 H-write (native cvt)
#pragma unroll
        for (int ebi = 0; ebi < 4; ++ebi) {
            int eb = eg1 * 4 + ebi;
            const u16* arow = Al + (eb * 16 + c) * 136 + q * 8;
            bf16x8 a0 = *(const bf16x8*)(arow);
            bf16x8 a1 = *(const bf16x8*)(arow + 32);
            bf16x8 a2 = *(const bf16x8*)(arow + 64);
            bf16x8 a3 = *(const bf16x8*)(arow + 96);
#pragma unroll
            for (int tt = 0; tt < 2; ++tt) {
                f32x4 acc = {0.f, 0.f, 0.f, 0.f};
                acc = __builtin_amdgcn_mfma_f32_16x16x32_bf16(w1f[tt][0], a0, acc, 0, 0, 0);
                acc = __builtin_amdgcn_mfma_f32_16x16x32_bf16(w1f[tt][1], a1, acc, 0, 0, 0);
                acc = __builtin_amdgcn_mfma_f32_16x16x32_bf16(w1f[tt][2], a2, acc, 0, 0, 0);
                acc = __builtin_amdgcn_mfma_f32_16x16x32_bf16(w1f[tt][3], a3, acc, 0, 0, 0);
                ushort4 hv;
                hv.x = cvt_bf(lrelu(acc[0] + b1q[tt].x));
                hv.y = cvt_bf(lrelu(acc[1] + b1q[tt].y));
                hv.z = cvt_bf(lrelu(acc[2] + b1q[tt].z));
                hv.w = cvt_bf(lrelu(acc[3] + b1q[tt].w));
                *(ushort4*)(Hl + (eb * 16 + c) * 136 + (tg * 2 + tt) * 16 + q * 4) = hv;
            }
        }
        lgkm_bar();   // bar2: Hl ready; Al-read(t) done before next commitStage

        // ---- GEMM2 + scatter epilogue
#pragma unroll
        for (int ebi = 0; ebi < 2; ++ebi) {
            int eb = eg2 * 2 + ebi;
            const u16* hrow = Hl + (eb * 16 + c) * 136 + q * 8;
            bf16x8 h0 = *(const bf16x8*)(hrow);
            bf16x8 h1 = *(const bf16x8*)(hrow + 32);
            bf16x8 h2 = *(const bf16x8*)(hrow + 64);
            bf16x8 h3 = *(const bf16x8*)(hrow + 96);
            int rb = eb * 16 + q * 4;
            int s0 = self_l[pb][rb], s1 = self_l[pb][rb + 1];
            int s2 = self_l[pb][rb + 2], s3 = self_l[pb][rb + 3];
            float a0 = attn_l[pb][rb], a1 = attn_l[pb][rb + 1];
            float a2v = attn_l[pb][rb + 2], a3 = attn_l[pb][rb + 3];
#pragma unroll
            for (int n2 = 0; n2 < 2; ++n2) {
                f32x4 m = {0.f, 0.f, 0.f, 0.f};
                m = __builtin_amdgcn_mfma_f32_16x16x32_bf16(h0, w2f[n2][0], m, 0, 0, 0);
                m = __builtin_amdgcn_mfma_f32_16x16x32_bf16(h1, w2f[n2][1], m, 0, 0, 0);
                m = __builtin_amdgcn_mfma_f32_16x16x32_bf16(h2, w2f[n2][2], m, 0, 0, 0);
                m = __builtin_amdgcn_mfma_f32_16x16x32_bf16(h3, w2f[n2][3], m, 0, 0, 0);
                int col = (ng * 2 + n2) * 16 + c;
                float v0 = a0 * (m[0] + b2v[n2]);
                float v1 = a1 * (m[1] + b2v[n2]);
                float v2 = a2v * (m[2] + b2v[n2]);
                float v3 = a3 * (m[3] + b2v[n2]);
                if (s0 == s1) v1 += v0; else atomicAdd(out + s0 * 64 + col, v0);
                if (s1 == s2) v2 += v1; else atomicAdd(out + s1 * 64 + col, v1);
                if (s2 == s3) v3 += v2; else atomicAdd(out + s2 * 64 + col, v2);
                atomicAdd(out + s3 * 64 + col, v3);   // stays in flight
            }
        }
    }
}

extern "C" void kernel_launch(void* const* d_in, const int* in_sizes, int n_in,
                              void* d_out, int out_size, void* d_ws, size_t ws_size,
                              hipStream_t stream) {
    const float* ew   = (const float*)d_in[0];
    const float* fea  = (const float*)d_in[1];
    const int* selfi  = (const int*)d_in[2];
    const int* nbri   = (const int*)d_in[3];
    const float* gw1  = (const float*)d_in[4];
    const float* gb1  = (const float*)d_in[5];
    const float* gw2  = (const float*)d_in[6];
    const float* gb2  = (const float*)d_in[7];
    const float* mw1  = (const float*)d_in[8];
    const float* mb1  = (const float*)d_in[9];
    const float* mw2  = (const float*)d_in[10];
    const float* mb2  = (const float*)d_in[11];
    float* out = (float*)d_out;
    char* ws = (char*)d_ws;

    float* e_buf = (float*)ws;                 // 3*M f32   (g, then e in place)
    u32* gmaxk   = (u32*)(ws + 12582912);      // 3*N u32
    float* denom = (float*)(ws + 15728640);    // 3*N f32
    u16* fea16   = (u16*)(ws + 18874368);      // N*64 bf16 (optional)
    const bool tab = ws_size >= (size_t)52428800;

    if (tab) {
        k_init<true><<<dim3(16384), dim3(256), 0, stream>>>(fea, out, gmaxk, denom, fea16);
        k_gate<true><<<dim3(512), dim3(384), 0, stream>>>(fea, fea16, selfi, nbri,
                                                          gw1, gb1, gw2, gb2, e_buf, gmaxk);
    } else {
        k_init<false><<<dim3(16384), dim3(256), 0, stream>>>(fea, out, gmaxk, denom, fea16);
        k_gate<false><<<dim3(512), dim3(384), 0, stream>>>(fea, fea16, selfi, nbri,
                                                           gw1, gb1, gw2, gb2, e_buf, gmaxk);
    }
    k_denom<<<dim3(1024), dim3(256), 0, stream>>>(ew, selfi, nbri, e_buf, gmaxk, denom);
    if (tab) {
        k_msg<true><<<dim3(512, 3), dim3(512), 0, stream>>>(fea, fea16, selfi, nbri,
                                                            mw1, mb1, mw2, mb2, e_buf, denom, out);
    } else {
        k_msg<false><<<dim3(512, 3), dim3(512), 0, stream>>>(fea, fea16, selfi, nbri,
                                                             mw1, mb1, mw2, mb2, e_buf, denom, out);
    }
}